// Round 1
// baseline (72.263 us; speedup 1.0000x reference)
//
#include <hip/hip_runtime.h>
#include <hip/hip_bf16.h>

#define BB 4096
#define CC 256
#define DD 512
#define SS 8

#define BM 64
#define BN 128
#define BK 64

typedef __attribute__((ext_vector_type(4))) float f32x4;
typedef __attribute__((ext_vector_type(8))) short s16x8;
typedef __attribute__((ext_vector_type(4))) short s16x4;

// RNE float -> bf16 bits (inputs are finite normals; matches v_cvt semantics)
static __device__ inline short f2bf(float f) {
    unsigned int u = __float_as_uint(f);
    u = u + 0x7FFFu + ((u >> 16) & 1u);
    return (short)(u >> 16);
}

__global__ void count_kernel(const int* __restrict__ subj, int* __restrict__ cnt) {
    int b = blockIdx.x * 256 + threadIdx.x;
    if (b < BB) atomicAdd(&cnt[subj[b]], 1);
}

__global__ void scatter_kernel(const int* __restrict__ subj, const int* __restrict__ cnt,
                               int* __restrict__ cursor, int* __restrict__ rows) {
    int b = blockIdx.x * 256 + threadIdx.x;
    if (b >= BB) return;
    int s = subj[b];
    int off = 0;
#pragma unroll
    for (int i = 0; i < SS; ++i) if (i < s) off += cnt[i];
    int p = atomicAdd(&cursor[s], 1);
    rows[off + p] = b;
}

__global__ __launch_bounds__(256) void gemm_kernel(
    const float* __restrict__ x, const float* __restrict__ w,
    const float* __restrict__ bias, const int* __restrict__ cnt,
    const int* __restrict__ rows, float* __restrict__ out)
{
    const int s = blockIdx.x >> 6;   // subject
    const int t = blockIdx.x & 63;   // row-tile within subject
    int n_s = 0, off = 0;
#pragma unroll
    for (int i = 0; i < SS; ++i) { int c = cnt[i]; if (i < s) off += c; if (i == s) n_s = c; }
    if (t * BM >= n_s) return;       // uniform across block: safe early exit
    int m_valid = n_s - t * BM; if (m_valid > BM) m_valid = BM;

    __shared__ __align__(16) short As[BM * BK];       // [row][k], XOR-swizzled rows
    __shared__ __align__(16) short Bs[BK / 8][BN][8]; // k-blocked: [kb][n][8]
    __shared__ int rows_l[BM];

    const int tid = threadIdx.x;
    if (tid < BM) {
        int idx = t * BM + tid;
        rows_l[tid] = (idx < n_s) ? rows[off + idx] : -1;
    }
    __syncthreads();

    const int bcol = blockIdx.y * BN;
    const float* wbase = w + (size_t)s * CC * DD + bcol;

    const int lane = tid & 63, wid = tid >> 6;
    const int wm = wid & 1, wn = wid >> 1;
    const int lr = lane & 15, lg = lane >> 4;

    f32x4 acc[2][4];
#pragma unroll
    for (int mf = 0; mf < 2; ++mf)
#pragma unroll
        for (int nf = 0; nf < 4; ++nf)
            acc[mf][nf] = (f32x4)0.0f;

    // staging assignments
    const int ar = tid >> 2;             // A row 0..63 (4 threads/row)
    const int ak = (tid & 3) * 16;       // 16 floats per thread
    const int grow = rows_l[ar];         // gathered global row (-1 = pad)
    const int bn = tid & 127;            // B column within tile
    const int kb0 = (tid >> 7) * 4;      // 4 k-blocks of 8 per thread

    for (int ks = 0; ks < CC / BK; ++ks) {
        // ---- stage A: x rows -> bf16, swizzled LDS
        {
            const float* xp = x + (size_t)(grow < 0 ? 0 : grow) * CC + ks * BK;
#pragma unroll
            for (int i = 0; i < 4; ++i) {
                int k = ak + i * 4;
                f32x4 v = (f32x4)0.0f;
                if (grow >= 0) v = *reinterpret_cast<const f32x4*>(xp + k);
                s16x4 p;
                p[0] = f2bf(v[0]); p[1] = f2bf(v[1]); p[2] = f2bf(v[2]); p[3] = f2bf(v[3]);
                *reinterpret_cast<s16x4*>(
                    reinterpret_cast<char*>(As) + ar * (BK * 2) + ((k * 2) ^ ((ar & 7) << 4))) = p;
            }
        }
        // ---- stage B: W rows -> bf16, k-blocked LDS
        {
#pragma unroll
            for (int i = 0; i < 4; ++i) {
                int kb = kb0 + i;
                const float* wp = wbase + (size_t)(ks * BK + kb * 8) * DD + bn;
                s16x8 p;
#pragma unroll
                for (int e = 0; e < 8; ++e) p[e] = f2bf(wp[(size_t)e * DD]);
                *reinterpret_cast<s16x8*>(&Bs[kb][bn][0]) = p;
            }
        }
        __syncthreads();

        // ---- fragments
        s16x8 af[2][2], bfr[4][2];
#pragma unroll
        for (int mf = 0; mf < 2; ++mf) {
            int row = wm * 32 + mf * 16 + lr;
#pragma unroll
            for (int kh = 0; kh < 2; ++kh) {
                int kf2 = (kh * 32 + lg * 8) * 2;
                af[mf][kh] = *reinterpret_cast<s16x8*>(
                    reinterpret_cast<char*>(As) + row * (BK * 2) + (kf2 ^ ((row & 7) << 4)));
            }
        }
#pragma unroll
        for (int nf = 0; nf < 4; ++nf) {
            int n = wn * 64 + nf * 16 + lr;
#pragma unroll
            for (int kh = 0; kh < 2; ++kh)
                bfr[nf][kh] = *reinterpret_cast<s16x8*>(&Bs[kh * 4 + lg][n][0]);
        }
        // ---- MFMA
#pragma unroll
        for (int mf = 0; mf < 2; ++mf)
#pragma unroll
            for (int nf = 0; nf < 4; ++nf)
#pragma unroll
                for (int kh = 0; kh < 2; ++kh)
                    acc[mf][nf] = __builtin_amdgcn_mfma_f32_16x16x32_bf16(
                        af[mf][kh], bfr[nf][kh], acc[mf][nf], 0, 0, 0);
        __syncthreads();
    }

    // ---- epilogue: + bias, scatter rows back
#pragma unroll
    for (int nf = 0; nf < 4; ++nf) {
        int col = bcol + wn * 64 + nf * 16 + lr;
        float bv = bias[s * DD + col];
#pragma unroll
        for (int mf = 0; mf < 2; ++mf) {
            int rl0 = wm * 32 + mf * 16 + lg * 4;
#pragma unroll
            for (int r = 0; r < 4; ++r) {
                int rl = rl0 + r;
                if (rl < m_valid) {
                    int g = rows_l[rl];
                    out[(size_t)g * DD + col] = acc[mf][nf][r] + bv;
                }
            }
        }
    }
}

extern "C" void kernel_launch(void* const* d_in, const int* in_sizes, int n_in,
                              void* d_out, int out_size, void* d_ws, size_t ws_size,
                              hipStream_t stream) {
    const float* x        = (const float*)d_in[0];
    const int*   subjects = (const int*)d_in[1];
    const float* weights  = (const float*)d_in[2];
    const float* bias     = (const float*)d_in[3];
    float* out = (float*)d_out;

    int* cnt    = (int*)d_ws;   // [8]
    int* cursor = cnt + 8;      // [8]
    int* rows   = cnt + 16;     // [4096]  (total ws use: 16.4 KB)

    hipMemsetAsync(cnt, 0, 16 * sizeof(int), stream);
    count_kernel<<<BB / 256, 256, 0, stream>>>(subjects, cnt);
    scatter_kernel<<<BB / 256, 256, 0, stream>>>(subjects, cnt, cursor, rows);
    dim3 grid(SS * (BB / BM), DD / BN);
    gemm_kernel<<<grid, 256, 0, stream>>>(x, weights, bias, cnt, rows, out);
}

// Round 2
// 25.014 us; speedup vs baseline: 2.8889x; 2.8889x over previous
//
#include <hip/hip_runtime.h>
#include <hip/hip_bf16.h>

#define BB 4096
#define CC 256
#define DD 512
#define SS 8

#define BM 64
#define BN 64
#define BK 64

typedef __attribute__((ext_vector_type(4))) float f32x4;
typedef __attribute__((ext_vector_type(8))) short s16x8;

// RNE float -> bf16 bits
static __device__ inline short f2bf(float f) {
    unsigned int u = __float_as_uint(f);
    u = u + 0x7FFFu + ((u >> 16) & 1u);
    return (short)(u >> 16);
}

// ws meta layout:
//   meta[0..7]   : per-subject counts
//   meta[8..15]  : per-subject exclusive offsets
//   meta[16]     : tile count
//   meta[17..95] : tile descriptors (s<<8 | row_tile)
//   meta+128     : rows[4096] (compacted row indices, grouped by subject)
__global__ __launch_bounds__(256) void prep_kernel(
    const float* __restrict__ x, const float* __restrict__ w,
    const int* __restrict__ subj, int* __restrict__ meta, int* __restrict__ rows,
    short* __restrict__ x_bf, short* __restrict__ w_bf)
{
    const int tid = threadIdx.x;
    if (blockIdx.x == 0) {
        // ---- binning: ballot-based histogram + placement (no global pre-zero)
        __shared__ int hist[SS], cur[SS];
        const int lane = tid & 63;
        const unsigned long long lt = (1ull << lane) - 1ull;
        if (tid < SS) hist[tid] = 0;
        __syncthreads();
        int sl[16];
#pragma unroll
        for (int i = 0; i < 16; ++i) sl[i] = subj[tid + i * 256];
#pragma unroll
        for (int i = 0; i < 16; ++i) {
            int s = sl[i];
            unsigned long long same = 0;
#pragma unroll
            for (int v = 0; v < SS; ++v) {
                unsigned long long mv = __ballot(s == v);
                if (s == v) same = mv;
            }
            int leader = __builtin_ctzll(same);
            if (lane == leader) atomicAdd(&hist[s], __popcll(same));
        }
        __syncthreads();
        if (tid == 0) {
            int o = 0, nt = 0;
            for (int v = 0; v < SS; ++v) {
                int c = hist[v];
                meta[v] = c; meta[SS + v] = o; cur[v] = o; o += c;
            }
            for (int v = 0; v < SS; ++v)
                for (int t = 0; t * BM < hist[v]; ++t)
                    meta[17 + nt++] = (v << 8) | t;
            meta[16] = nt;
        }
        __syncthreads();
#pragma unroll
        for (int i = 0; i < 16; ++i) {
            int s = sl[i];
            unsigned long long same = 0;
#pragma unroll
            for (int v = 0; v < SS; ++v) {
                unsigned long long mv = __ballot(s == v);
                if (s == v) same = mv;
            }
            int leader = __builtin_ctzll(same);
            int rank = __popcll(same & lt);
            int base = 0;
            if (lane == leader) base = atomicAdd(&cur[s], __popcll(same));
            base = __shfl(base, leader);
            rows[base + rank] = tid + i * 256;
        }
    } else if (blockIdx.x <= 512) {
        // ---- x -> bf16, linear [4096][256]
        int t = (blockIdx.x - 1) * 256 + tid;   // [0, 131072)
        int base = t * 8;
        f32x4 v0 = *reinterpret_cast<const f32x4*>(x + base);
        f32x4 v1 = *reinterpret_cast<const f32x4*>(x + base + 4);
        s16x8 p;
        p[0] = f2bf(v0[0]); p[1] = f2bf(v0[1]); p[2] = f2bf(v0[2]); p[3] = f2bf(v0[3]);
        p[4] = f2bf(v1[0]); p[5] = f2bf(v1[1]); p[6] = f2bf(v1[2]); p[7] = f2bf(v1[3]);
        *reinterpret_cast<s16x8*>(x_bf + base) = p;
    } else {
        // ---- w -> bf16, k-blocked [s][kb][n][8]  (kb = k/8, inner = k%8)
        int u = (blockIdx.x - 513) * 256 + tid; // [0, 131072)
        int n = u & 511, kb = (u >> 9) & 31, s = u >> 14;
        const float* wp = w + ((size_t)(s * CC + kb * 8)) * DD + n;
        s16x8 p;
#pragma unroll
        for (int e = 0; e < 8; ++e) p[e] = f2bf(wp[(size_t)e * DD]);
        *reinterpret_cast<s16x8*>(w_bf + (size_t)u * 8) = p;
    }
}

__global__ __launch_bounds__(256) void gemm_kernel(
    const short* __restrict__ x_bf, const short* __restrict__ w_bf,
    const float* __restrict__ bias, const int* __restrict__ meta,
    const int* __restrict__ rows, float* __restrict__ out)
{
    const int nt = meta[16];
    if ((int)blockIdx.x >= nt) return;
    const int d = meta[17 + blockIdx.x];
    const int s = d >> 8, t = d & 255;
    const int n_s = meta[s], off = meta[SS + s];
    int m_valid = n_s - t * BM; if (m_valid > BM) m_valid = BM;

    __shared__ __align__(16) short As[BM * BK];       // [row][k], XOR-swizzled rows (8KB)
    __shared__ __align__(16) short Bs[BK / 8][BN][8]; // k-blocked (8KB)
    __shared__ int rows_l[BM];

    const int tid = threadIdx.x;
    if (tid < BM) {
        int idx = t * BM + tid;
        rows_l[tid] = (idx < n_s) ? rows[off + idx] : -1;
    }
    __syncthreads();

    const int bcol = blockIdx.y * BN;
    const int lane = tid & 63, wid = tid >> 6;
    const int wm = wid & 1, wn = wid >> 1;
    const int lr = lane & 15, lg = lane >> 4;

    f32x4 acc[2][2];
#pragma unroll
    for (int mf = 0; mf < 2; ++mf)
#pragma unroll
        for (int nf = 0; nf < 2; ++nf)
            acc[mf][nf] = (f32x4)0.0f;

    const int ar = tid >> 2;           // A row (4 threads/row)
    const int ac = (tid & 3) * 2;      // 16B-chunk base within row
    const int grow = rows_l[ar];
    const short* xp = x_bf + (size_t)(grow < 0 ? 0 : grow) * CC + ac * 8;
    const short* wsrc = w_bf + ((size_t)(s * 32) * 512 + bcol) * 8;

    for (int ks = 0; ks < CC / BK; ++ks) {
        // ---- stage A (bf16, swizzled)
#pragma unroll
        for (int i = 0; i < 2; ++i) {
            s16x8 v = (s16x8)(short)0;
            if (grow >= 0) v = *reinterpret_cast<const s16x8*>(xp + ks * BK + i * 8);
            int c = ac + i;
            *reinterpret_cast<s16x8*>(reinterpret_cast<char*>(As)
                + ar * 128 + ((c * 16) ^ ((ar & 7) << 4))) = v;
        }
        // ---- stage B (straight 16B copies from k-blocked w_bf)
#pragma unroll
        for (int i = 0; i < 2; ++i) {
            int ch = tid + i * 256;
            int kb = ch >> 6, nn = ch & 63;
            *reinterpret_cast<s16x8*>(&Bs[kb][nn][0]) =
                *reinterpret_cast<const s16x8*>(wsrc + ((size_t)(ks * 8 + kb) * 512 + nn) * 8);
        }
        __syncthreads();

        s16x8 af[2][2], bfr[2][2];
#pragma unroll
        for (int mf = 0; mf < 2; ++mf) {
            int row = wm * 32 + mf * 16 + lr;
#pragma unroll
            for (int kh = 0; kh < 2; ++kh) {
                int kf2 = (kh * 32 + lg * 8) * 2;
                af[mf][kh] = *reinterpret_cast<s16x8*>(reinterpret_cast<char*>(As)
                    + row * 128 + (kf2 ^ ((row & 7) << 4)));
            }
        }
#pragma unroll
        for (int nf = 0; nf < 2; ++nf) {
            int n = wn * 32 + nf * 16 + lr;
#pragma unroll
            for (int kh = 0; kh < 2; ++kh)
                bfr[nf][kh] = *reinterpret_cast<s16x8*>(&Bs[kh * 4 + lg][n][0]);
        }
#pragma unroll
        for (int mf = 0; mf < 2; ++mf)
#pragma unroll
            for (int nf = 0; nf < 2; ++nf)
#pragma unroll
                for (int kh = 0; kh < 2; ++kh)
                    acc[mf][nf] = __builtin_amdgcn_mfma_f32_16x16x32_bf16(
                        af[mf][kh], bfr[nf][kh], acc[mf][nf], 0, 0, 0);
        __syncthreads();
    }

    // ---- epilogue: + bias, scatter rows back
#pragma unroll
    for (int nf = 0; nf < 2; ++nf) {
        int col = bcol + wn * 32 + nf * 16 + lr;
        float bv = bias[s * DD + col];
#pragma unroll
        for (int mf = 0; mf < 2; ++mf) {
            int rl0 = wm * 32 + mf * 16 + lg * 4;
#pragma unroll
            for (int r = 0; r < 4; ++r) {
                int rl = rl0 + r;
                if (rl < m_valid) {
                    int g = rows_l[rl];
                    out[(size_t)g * DD + col] = acc[mf][nf][r] + bv;
                }
            }
        }
    }
}

extern "C" void kernel_launch(void* const* d_in, const int* in_sizes, int n_in,
                              void* d_out, int out_size, void* d_ws, size_t ws_size,
                              hipStream_t stream) {
    const float* x        = (const float*)d_in[0];
    const int*   subjects = (const int*)d_in[1];
    const float* weights  = (const float*)d_in[2];
    const float* bias     = (const float*)d_in[3];
    float* out = (float*)d_out;

    int* meta  = (int*)d_ws;
    int* rows  = meta + 128;
    short* x_bf = (short*)(rows + BB);          // 2 MB
    short* w_bf = x_bf + (size_t)BB * CC;       // 2 MB

    prep_kernel<<<1025, 256, 0, stream>>>(x, weights, subjects, meta, rows, x_bf, w_bf);
    dim3 grid(72, DD / BN);
    gemm_kernel<<<grid, 256, 0, stream>>>(x_bf, w_bf, bias, meta, rows, out);
}